// Round 5
// baseline (85.674 us; speedup 1.0000x reference)
//
#include <hip/hip_runtime.h>

// OrdFilter: 5x5 reflect-pad window, mean of top-9. In/out fp32 (16,1,512,512).
//
// Direct-global version: no LDS, no barrier. Each thread computes 8 consecutive
// output pixels in x. Its 12-col x 5-row input window is read straight from
// global: 2 aligned float4 loads (interior 8 cols, always in-bounds) + 4 scalar
// halo loads with branchless reflected indices, per row. 30 independent VMEM
// ops -> full memory-level parallelism; row reuse (5x) hits L1/L2.
//
// Selection network (verified rounds 2-3, absmax 2^-7):
//   - 12 shared vertical 5-columns sorted once (optimal 9-CE sorter)
//   - 6 adjacent-pair merges -> sorted-10 (inf-elided bitonic merge, 15 CE)
//   - 5 shared top9s (cross-max 9 + valley-sort 13 CE), each feeds 1-2 px
//   - per px: fold leftover sorted column (5 maxes) + sum, /9
// ~85 VALU ops/px. All arrays constant-indexed & fully unrolled -> VGPRs.

#define H 512
#define W 512
#define BY 16            // output rows per block
#define TXD 16           // threads in x
#define SPX 8            // pixels per thread (x strip)
#define BW (TXD * SPX)   // 128 output cols per block

__device__ __forceinline__ void ce(float& a, float& b) {
    const float lo = fminf(a, b);
    const float hi = fmaxf(a, b);
    a = lo;
    b = hi;
}

// optimal 9-CE ascending 5-sorter
__device__ __forceinline__ void sort5(float* a) {
    ce(a[0], a[1]); ce(a[3], a[4]);
    ce(a[2], a[4]); ce(a[2], a[3]);
    ce(a[1], a[4]); ce(a[0], a[3]);
    ce(a[0], a[2]); ce(a[1], a[3]);
    ce(a[1], a[2]);
}

// merge two ascending 5-seqs -> ascending S[10] (inf-elided bitonic merge-16)
__device__ __forceinline__ void merge55(const float A[5], const float B[5], float S[10]) {
    float t0 = A[3], u0 = B[4]; ce(t0, u0);
    float t1 = A[4], u1 = B[3]; ce(t1, u1);
    float L0 = A[0], L1 = A[1], L2 = A[2], L3 = t0, L4 = t1, L5 = B[2], L6 = B[1], L7 = B[0];
    ce(L0, L4); ce(L1, L5); ce(L2, L6); ce(L3, L7);
    ce(L0, L2); ce(L1, L3); ce(L4, L6); ce(L5, L7);
    ce(L0, L1); ce(L2, L3); ce(L4, L5); ce(L6, L7);
    ce(u0, u1);
    S[0] = L0; S[1] = L1; S[2] = L2; S[3] = L3;
    S[4] = L4; S[5] = L5; S[6] = L6; S[7] = L7;
    S[8] = u0; S[9] = u1;
}

// sorted (ascending) top-9 of two ascending 10-seqs: cross-max valley + sort
__device__ __forceinline__ void top9_sorted(const float A[10], const float B[10], float S[9]) {
    float d0 = fmaxf(A[1], B[9]);
    float d1 = fmaxf(A[2], B[8]);
    float d2 = fmaxf(A[3], B[7]);
    float d3 = fmaxf(A[4], B[6]);
    float d4 = fmaxf(A[5], B[5]);
    float d5 = fmaxf(A[6], B[4]);
    float d6 = fmaxf(A[7], B[3]);
    float d7 = fmaxf(A[8], B[2]);
    float d8 = fmaxf(A[9], B[1]);
    ce(d0, d8);  // d8 = global max; d0..d7 bitonic
    ce(d0, d4); ce(d1, d5); ce(d2, d6); ce(d3, d7);
    ce(d0, d2); ce(d1, d3); ce(d4, d6); ce(d5, d7);
    ce(d0, d1); ce(d2, d3); ce(d4, d5); ce(d6, d7);
    S[0] = d0; S[1] = d1; S[2] = d2; S[3] = d3;
    S[4] = d4; S[5] = d5; S[6] = d6; S[7] = d7; S[8] = d8;
}

// mean of top-9 of (S[9] asc ∪ C[5] asc) via the (9,5,k=9) cross-max
__device__ __forceinline__ float final_mean(const float S[9], const float C[5]) {
    const float s = fmaxf(S[0], C[4]) + fmaxf(S[1], C[3]) + fmaxf(S[2], C[2]) +
                    fmaxf(S[3], C[1]) + fmaxf(S[4], C[0]) + S[5] + S[6] + S[7] + S[8];
    return s * (1.0f / 9.0f);
}

__device__ __forceinline__ int reflect(int v, int n) {
    v = v < 0 ? -v : v;
    return v >= n ? 2 * n - 2 - v : v;
}

__global__ __launch_bounds__(256) void ordfilter_kernel(
    const float* __restrict__ in, float* __restrict__ out) {
    const int bx = blockIdx.x * BW;
    const int by = blockIdx.y * BY;
    const int b  = blockIdx.z;
    const float* __restrict__ src = in  + (size_t)b * H * W;
    float* __restrict__ dst       = out + (size_t)b * H * W;

    const int tx   = threadIdx.x;
    const int ty   = threadIdx.y;
    const int base = bx + tx * SPX;  // first output col; cols base..base+7 interior
    const int oy   = by + ty;

    // reflected halo columns (x); identity for interior threads, branchless
    const int hx0 = reflect(base - 2, W);
    const int hx1 = reflect(base - 1, W);
    const int hx2 = reflect(base + 8, W);
    const int hx3 = reflect(base + 9, W);

    // ---- gather 12 cols x 5 rows straight from global ----
    float c[12][5];
    #pragma unroll
    for (int i = 0; i < 5; ++i) {
        const int gy = reflect(oy + i - 2, H);
        const float* __restrict__ row = src + gy * W;
        const float4 v0 = *reinterpret_cast<const float4*>(row + base);      // 32B-aligned
        const float4 v1 = *reinterpret_cast<const float4*>(row + base + 4);
        c[0][i]  = row[hx0];
        c[1][i]  = row[hx1];
        c[2][i]  = v0.x; c[3][i] = v0.y; c[4][i] = v0.z; c[5][i] = v0.w;
        c[6][i]  = v1.x; c[7][i] = v1.y; c[8][i] = v1.z; c[9][i] = v1.w;
        c[10][i] = row[hx2];
        c[11][i] = row[hx3];
    }

    // ---- sort the 12 shared columns ----
    #pragma unroll
    for (int k = 0; k < 12; ++k) sort5(c[k]);

    // ---- pair merges -> 6 sorted-10s ----
    float E[6][10];
    #pragma unroll
    for (int t = 0; t < 6; ++t) merge55(c[2 * t], c[2 * t + 1], E[t]);

    // ---- 5 shared top9s; per-pixel fold of leftover column ----
    // px 2t   = E_t ∪ E_{t+1} ∪ col(2t+4) ;  px 2t+1 = E_{t+1} ∪ E_{t+2} ∪ col(2t+1)
    float r[8];
    #pragma unroll
    for (int t = 0; t < 5; ++t) {
        float D[9];
        top9_sorted(E[t], E[t + 1], D);
        if (t == 0) {
            r[0] = final_mean(D, c[4]);
        } else if (t == 4) {
            r[7] = final_mean(D, c[7]);
        } else {
            r[2 * t - 1] = final_mean(D, c[2 * t - 1]);
            r[2 * t]     = final_mean(D, c[2 * t + 4]);
        }
    }

    float* orow = dst + oy * W + base;
    float4 o0; o0.x = r[0]; o0.y = r[1]; o0.z = r[2]; o0.w = r[3];
    float4 o1; o1.x = r[4]; o1.y = r[5]; o1.z = r[6]; o1.w = r[7];
    *reinterpret_cast<float4*>(orow)     = o0;
    *reinterpret_cast<float4*>(orow + 4) = o1;
}

extern "C" void kernel_launch(void* const* d_in, const int* in_sizes, int n_in,
                              void* d_out, int out_size, void* d_ws, size_t ws_size,
                              hipStream_t stream) {
    const float* in = (const float*)d_in[0];
    float* out      = (float*)d_out;
    dim3 grid(W / BW, H / BY, 16);  // 4 x 32 x 16 = 2048 blocks
    dim3 block(TXD, BY);            // 256 threads
    ordfilter_kernel<<<grid, block, 0, stream>>>(in, out);
}